// Round 1
// baseline (8427.740 us; speedup 1.0000x reference)
//
#include <hip/hip_runtime.h>
#include <hip/hip_bf16.h>

#define N_NODES 100000
#define IN_DIM 128
#define HID 64
#define OUT_DIM 32
#define N_LAYERS 3

// ---------------------------------------------------------------------------
// Kernel 1: h = x @ W_in + b_in          [N,128] @ [128,64] -> [N,64]
// Block = 256 threads, 16 nodes per block (100000 = 6250 * 16).
// W_in (32 KB) staged in LDS once per block; x rows staged 4-at-a-time.
// ---------------------------------------------------------------------------
__global__ __launch_bounds__(256) void k_proj(const float* __restrict__ x,
                                              const float* __restrict__ W,
                                              const float* __restrict__ b,
                                              float* __restrict__ h) {
    __shared__ float sW[IN_DIM * HID];   // 32 KB
    __shared__ float sx[4][IN_DIM];      // 2 KB
    for (int i = threadIdx.x; i < IN_DIM * HID; i += 256) sW[i] = W[i];

    const int j  = threadIdx.x & 63;   // output feature
    const int nl = threadIdx.x >> 6;   // node-in-group 0..3
    const float bj = b[j];
    const int base = blockIdx.x * 16;

    for (int it = 0; it < 4; ++it) {
        const int n0 = base + it * 4;
        __syncthreads();   // protects sx reuse (and sW load on it==0)
        // stage 4 rows (4*128 floats = 256 float2) cooperatively
        {
            const float2* xv = (const float2*)(x + (size_t)n0 * IN_DIM);
            float2* sv = (float2*)&sx[0][0];
            sv[threadIdx.x] = xv[threadIdx.x];
        }
        __syncthreads();
        const int n = n0 + nl;
        float acc = bj;
#pragma unroll
        for (int k = 0; k < IN_DIM; ++k)
            acc = fmaf(sx[nl][k], sW[k * HID + j], acc);
        h[(size_t)n * HID + j] = acc;
    }
}

// ---------------------------------------------------------------------------
// Kernel 2: edge scatter.  agg[dst] += h[src] * w
// Quarter-wave (16 lanes) per edge; each lane: float4 gather + 4 f32 atomics.
// ---------------------------------------------------------------------------
__global__ __launch_bounds__(256) void k_scatter(const float* __restrict__ h,
                                                 const int* __restrict__ src,
                                                 const int* __restrict__ dst,
                                                 const float* __restrict__ ew,
                                                 float* __restrict__ agg,
                                                 int E) {
    const int t = blockIdx.x * 256 + threadIdx.x;
    const int e    = t >> 4;
    const int lane = t & 15;
    if (e >= E) return;
    const int   s = src[e];
    const int   d = dst[e];
    const float w = ew[e];
    const float4 v = ((const float4*)(h + (size_t)s * HID))[lane];
    float* a = agg + (size_t)d * HID + lane * 4;
    atomicAdd(a + 0, v.x * w);
    atomicAdd(a + 1, v.y * w);
    atomicAdd(a + 2, v.z * w);
    atomicAdd(a + 3, v.w * w);
}

// ---------------------------------------------------------------------------
// Kernel 3: h = relu((h + agg) @ W_g[l] + b_g[l])   in-place, row-wise.
// Block = 256 threads, 16 nodes/block. W (16 KB) in LDS.
// In-place safety: all global reads of row n happen before the barrier,
// the write after; no other block touches row n.
// ---------------------------------------------------------------------------
__global__ __launch_bounds__(256) void k_update(float* __restrict__ h,
                                                const float* __restrict__ agg,
                                                const float* __restrict__ W,
                                                const float* __restrict__ b) {
    __shared__ float sW[HID * HID];   // 16 KB
    __shared__ float sin[4][HID];
    for (int i = threadIdx.x; i < HID * HID; i += 256) sW[i] = W[i];

    const int j  = threadIdx.x & 63;
    const int nl = threadIdx.x >> 6;
    const float bj = b[j];
    const int base = blockIdx.x * 16;

    for (int it = 0; it < 4; ++it) {
        const int n = base + it * 4 + nl;
        __syncthreads();   // sin reuse + sW ready
        sin[nl][j] = h[(size_t)n * HID + j] + agg[(size_t)n * HID + j];
        __syncthreads();
        float acc = bj;
#pragma unroll
        for (int k = 0; k < HID; ++k)
            acc = fmaf(sin[nl][k], sW[k * HID + j], acc);
        h[(size_t)n * HID + j] = fmaxf(acc, 0.0f);
    }
}

// ---------------------------------------------------------------------------
// Kernel 4: out = h @ W_out + b_out      [N,64] @ [64,32]
// Block = 256 threads, 32 nodes/block (100000 = 3125 * 32), 8 nodes per pass.
// ---------------------------------------------------------------------------
__global__ __launch_bounds__(256) void k_out(const float* __restrict__ h,
                                             const float* __restrict__ W,
                                             const float* __restrict__ b,
                                             float* __restrict__ out) {
    __shared__ float sW[HID * OUT_DIM];  // 8 KB
    __shared__ float sin[8][HID];
    for (int i = threadIdx.x; i < HID * OUT_DIM; i += 256) sW[i] = W[i];

    const int j  = threadIdx.x & 31;   // output feature
    const int nl = threadIdx.x >> 5;   // 0..7
    const float bj = b[j];
    const int base = blockIdx.x * 32;

    for (int it = 0; it < 4; ++it) {
        const int n = base + it * 8 + nl;
        __syncthreads();
        sin[nl][j]      = h[(size_t)n * HID + j];
        sin[nl][j + 32] = h[(size_t)n * HID + j + 32];
        __syncthreads();
        float acc = bj;
#pragma unroll
        for (int k = 0; k < HID; ++k)
            acc = fmaf(sin[nl][k], sW[k * OUT_DIM + j], acc);
        out[(size_t)n * OUT_DIM + j] = acc;
    }
}

extern "C" void kernel_launch(void* const* d_in, const int* in_sizes, int n_in,
                              void* d_out, int out_size, void* d_ws, size_t ws_size,
                              hipStream_t stream) {
    const float* x     = (const float*)d_in[0];
    const int*   ei    = (const int*)d_in[1];   // [2, E] int
    const float* ew    = (const float*)d_in[2];
    const float* W_in  = (const float*)d_in[3];
    const float* b_in  = (const float*)d_in[4];
    const float* W_g   = (const float*)d_in[5];
    const float* b_g   = (const float*)d_in[6];
    const float* W_out = (const float*)d_in[7];
    const float* b_out = (const float*)d_in[8];
    float* out = (float*)d_out;

    const int E = in_sizes[2];          // 3,200,000
    const int* src = ei;
    const int* dst = ei + E;

    float* h   = (float*)d_ws;                       // N*HID fp32 = 25.6 MB
    float* agg = h + (size_t)N_NODES * HID;          // N*HID fp32 = 25.6 MB

    // 1) input projection
    k_proj<<<N_NODES / 16, 256, 0, stream>>>(x, W_in, b_in, h);

    // 2) three message-passing layers
    const int scatter_blocks = (E * 16 + 255) / 256;  // 200000
    for (int l = 0; l < N_LAYERS; ++l) {
        hipMemsetAsync(agg, 0, (size_t)N_NODES * HID * sizeof(float), stream);
        k_scatter<<<scatter_blocks, 256, 0, stream>>>(h, src, dst, ew, agg, E);
        k_update<<<N_NODES / 16, 256, 0, stream>>>(h, agg,
                                                   W_g + (size_t)l * HID * HID,
                                                   b_g + (size_t)l * HID);
    }

    // 3) output projection
    k_out<<<N_NODES / 32, 256, 0, stream>>>(h, W_out, b_out, out);
}

// Round 2
// 1140.816 us; speedup vs baseline: 7.3875x; 7.3875x over previous
//
#include <hip/hip_runtime.h>
#include <hip/hip_bf16.h>

#define N_NODES 100000
#define IN_DIM 128
#define HID 64
#define OUT_DIM 32
#define N_LAYERS 3
#define SCAN_BLK 512
#define NBLK ((N_NODES + SCAN_BLK - 1) / SCAN_BLK)   // 196

// ---------------------------------------------------------------------------
// Kernel 1: h = x @ W_in + b_in          [N,128] @ [128,64] -> [N,64]
// ---------------------------------------------------------------------------
__global__ __launch_bounds__(256) void k_proj(const float* __restrict__ x,
                                              const float* __restrict__ W,
                                              const float* __restrict__ b,
                                              float* __restrict__ h) {
    __shared__ float sW[IN_DIM * HID];   // 32 KB
    __shared__ float sx[4][IN_DIM];      // 2 KB
    for (int i = threadIdx.x; i < IN_DIM * HID; i += 256) sW[i] = W[i];

    const int j  = threadIdx.x & 63;   // output feature
    const int nl = threadIdx.x >> 6;   // node-in-group 0..3
    const float bj = b[j];
    const int base = blockIdx.x * 16;

    for (int it = 0; it < 4; ++it) {
        const int n0 = base + it * 4;
        __syncthreads();
        {
            const float2* xv = (const float2*)(x + (size_t)n0 * IN_DIM);
            float2* sv = (float2*)&sx[0][0];
            sv[threadIdx.x] = xv[threadIdx.x];
        }
        __syncthreads();
        const int n = n0 + nl;
        float acc = bj;
#pragma unroll
        for (int k = 0; k < IN_DIM; ++k)
            acc = fmaf(sx[nl][k], sW[k * HID + j], acc);
        h[(size_t)n * HID + j] = acc;
    }
}

// ---------------------------------------------------------------------------
// CSR build: histogram -> exclusive scan -> fill (edge data packed as int2)
// ---------------------------------------------------------------------------
__global__ __launch_bounds__(256) void k_hist(const int* __restrict__ dst,
                                              int* __restrict__ deg, int E) {
    int e = blockIdx.x * 256 + threadIdx.x;
    if (e < E) atomicAdd(&deg[dst[e]], 1);
}

__global__ __launch_bounds__(SCAN_BLK) void k_scan_block(const int* __restrict__ deg,
                                                         int* __restrict__ off,
                                                         int* __restrict__ bsum) {
    __shared__ int s[SCAN_BLK];
    const int t = threadIdx.x;
    const int i = blockIdx.x * SCAN_BLK + t;
    int v = (i < N_NODES) ? deg[i] : 0;
    s[t] = v;
    __syncthreads();
    for (int d = 1; d < SCAN_BLK; d <<= 1) {
        int a = (t >= d) ? s[t - d] : 0;
        __syncthreads();
        s[t] += a;
        __syncthreads();
    }
    if (i < N_NODES) off[i] = s[t] - v;           // exclusive within block
    if (t == SCAN_BLK - 1) bsum[blockIdx.x] = s[t];
}

__global__ __launch_bounds__(256) void k_scan_bsum(int* __restrict__ bsum) {
    __shared__ int s[256];
    const int t = threadIdx.x;
    int v = (t < NBLK) ? bsum[t] : 0;
    s[t] = v;
    __syncthreads();
    for (int d = 1; d < 256; d <<= 1) {
        int a = (t >= d) ? s[t - d] : 0;
        __syncthreads();
        s[t] += a;
        __syncthreads();
    }
    if (t < NBLK) bsum[t] = s[t] - v;             // exclusive
}

__global__ __launch_bounds__(SCAN_BLK) void k_scan_add(int* __restrict__ off,
                                                       int* __restrict__ cur,
                                                       const int* __restrict__ bsum) {
    int i = blockIdx.x * SCAN_BLK + threadIdx.x;
    if (i < N_NODES) {
        int o = off[i] + bsum[blockIdx.x];
        off[i] = o;
        cur[i] = o;
    }
}

__global__ __launch_bounds__(256) void k_fill(const int* __restrict__ src,
                                              const int* __restrict__ dst,
                                              const float* __restrict__ ew,
                                              int* __restrict__ cur,
                                              int2* __restrict__ ed, int E) {
    int e = blockIdx.x * 256 + threadIdx.x;
    if (e < E) {
        int d = dst[e];
        int pos = atomicAdd(&cur[d], 1);
        ed[pos] = make_int2(src[e], __float_as_int(ew[e]));
    }
}
// after k_fill completes, cur[n] == end offset of node n's edge list

// ---------------------------------------------------------------------------
// Fused layer: h_out[n] = relu( (h_in[n] + sum_e w_e * h_in[src_e]) @ W + b )
// Quarter-wave (16 lanes, float4 each) per node gathers with NO atomics;
// GEMM done in-block via LDS. 16 nodes per 256-thread block.
// ---------------------------------------------------------------------------
__global__ __launch_bounds__(256) void k_gather_update(
        const float* __restrict__ hin, float* __restrict__ hout,
        const int2* __restrict__ ed, const int* __restrict__ off,
        const int* __restrict__ end, const float* __restrict__ W,
        const float* __restrict__ b) {
    __shared__ float sW[HID * HID];     // 16 KB
    __shared__ float sAgg[16][HID];     // 4 KB
    for (int i = threadIdx.x; i < HID * HID; i += 256) sW[i] = W[i];

    const int qw   = threadIdx.x >> 4;  // node-in-block 0..15
    const int lane = threadIdx.x & 15;  // feature quad 0..15
    const int n = blockIdx.x * 16 + qw;

    // self term + weighted neighbor sum (register accumulation, no atomics)
    float4 acc = ((const float4*)(hin + (size_t)n * HID))[lane];
    const int i0 = off[n], i1 = end[n];
    for (int i = i0; i < i1; ++i) {
        const int2 e = ed[i];
        const float w = __int_as_float(e.y);
        const float4 v = ((const float4*)(hin + (size_t)e.x * HID))[lane];
        acc.x = fmaf(v.x, w, acc.x);
        acc.y = fmaf(v.y, w, acc.y);
        acc.z = fmaf(v.z, w, acc.z);
        acc.w = fmaf(v.w, w, acc.w);
    }
    ((float4*)&sAgg[qw][0])[lane] = acc;
    __syncthreads();

    // GEMM: 256 threads = 64 features x 4 node-groups; 4 passes cover 16 nodes
    const int j = threadIdx.x & 63;
    const int g = threadIdx.x >> 6;     // 0..3
    const float bj = b[j];
#pragma unroll
    for (int p = 0; p < 4; ++p) {
        const int node = g * 4 + p;
        float a = bj;
#pragma unroll
        for (int k = 0; k < HID; ++k)
            a = fmaf(sAgg[node][k], sW[k * HID + j], a);
        hout[(size_t)(blockIdx.x * 16 + node) * HID + j] = fmaxf(a, 0.0f);
    }
}

// ---------------------------------------------------------------------------
// Output: out = h @ W_out + b_out      [N,64] @ [64,32]
// ---------------------------------------------------------------------------
__global__ __launch_bounds__(256) void k_out(const float* __restrict__ h,
                                             const float* __restrict__ W,
                                             const float* __restrict__ b,
                                             float* __restrict__ out) {
    __shared__ float sW[HID * OUT_DIM];  // 8 KB
    __shared__ float sin[8][HID];
    for (int i = threadIdx.x; i < HID * OUT_DIM; i += 256) sW[i] = W[i];

    const int j  = threadIdx.x & 31;
    const int nl = threadIdx.x >> 5;
    const float bj = b[j];
    const int base = blockIdx.x * 32;

    for (int it = 0; it < 4; ++it) {
        const int n = base + it * 8 + nl;
        __syncthreads();
        sin[nl][j]      = h[(size_t)n * HID + j];
        sin[nl][j + 32] = h[(size_t)n * HID + j + 32];
        __syncthreads();
        float acc = bj;
#pragma unroll
        for (int k = 0; k < HID; ++k)
            acc = fmaf(sin[nl][k], sW[k * OUT_DIM + j], acc);
        out[(size_t)n * OUT_DIM + j] = acc;
    }
}

extern "C" void kernel_launch(void* const* d_in, const int* in_sizes, int n_in,
                              void* d_out, int out_size, void* d_ws, size_t ws_size,
                              hipStream_t stream) {
    const float* x     = (const float*)d_in[0];
    const int*   ei    = (const int*)d_in[1];   // [2, E] int
    const float* ew    = (const float*)d_in[2];
    const float* W_in  = (const float*)d_in[3];
    const float* b_in  = (const float*)d_in[4];
    const float* W_g   = (const float*)d_in[5];
    const float* b_g   = (const float*)d_in[6];
    const float* W_out = (const float*)d_in[7];
    const float* b_out = (const float*)d_in[8];
    float* out = (float*)d_out;

    const int E = in_sizes[2];          // 3,200,000
    const int* src = ei;
    const int* dst = ei + E;

    // workspace layout (int2 first for 8B alignment): ~77.6 MB total
    int2*  ed   = (int2*)d_ws;                          // E * 8 B   = 25.6 MB
    float* hA   = (float*)(ed + E);                     // 25.6 MB
    float* hB   = hA + (size_t)N_NODES * HID;           // 25.6 MB
    int*   off  = (int*)(hB + (size_t)N_NODES * HID);   // 400 KB
    int*   cur  = off + N_NODES;                        // 400 KB (deg, then cursor/end)
    int*   bsum = cur + N_NODES;                        // 1 KB

    // 1) input projection (overlaps CSR build region? no deps — fine in-order)
    k_proj<<<N_NODES / 16, 256, 0, stream>>>(x, W_in, b_in, hA);

    // 2) CSR build (by destination), rebuilt every call (ws is re-poisoned)
    hipMemsetAsync(cur, 0, N_NODES * sizeof(int), stream);          // deg := 0
    k_hist<<<(E + 255) / 256, 256, 0, stream>>>(dst, cur, E);
    k_scan_block<<<NBLK, SCAN_BLK, 0, stream>>>(cur, off, bsum);
    k_scan_bsum<<<1, 256, 0, stream>>>(bsum);
    k_scan_add<<<NBLK, SCAN_BLK, 0, stream>>>(off, cur, bsum);      // cur := off
    k_fill<<<(E + 255) / 256, 256, 0, stream>>>(src, dst, ew, cur, ed, E);

    // 3) three fused message-passing + update layers (ping-pong hA/hB)
    float* hi = hA;
    float* ho = hB;
    for (int l = 0; l < N_LAYERS; ++l) {
        k_gather_update<<<N_NODES / 16, 256, 0, stream>>>(
            hi, ho, ed, off, cur, W_g + (size_t)l * HID * HID, b_g + (size_t)l * HID);
        float* t = hi; hi = ho; ho = t;
    }

    // 4) output projection (hi holds the final h after 3 swaps)
    k_out<<<N_NODES / 32, 256, 0, stream>>>(hi, W_out, b_out, out);
}